// Round 11
// baseline (834.556 us; speedup 1.0000x reference)
//
#include <hip/hip_runtime.h>
#include <hip/hip_bf16.h>
#include <stdint.h>

#define M_TOTAL 16384
#define N_TOTAL 4096
#define K_TOTAL 4096
#define NT32 (K_TOTAL / 32)    // 128 K-steps of 32

typedef __attribute__((ext_vector_type(8))) short bf16x8;
typedef __attribute__((ext_vector_type(4))) float f32x4;

__device__ __forceinline__ void gload_lds16(const void* g, void* l) {
    __builtin_amdgcn_global_load_lds(
        (const __attribute__((address_space(1))) uint32_t*)g,
        (__attribute__((address_space(3))) uint32_t*)l, 16, 0, 0);
}

// ---------------------------------------------------------------------------
// Kernel 0: X f32 -> bf16.
// ---------------------------------------------------------------------------
__global__ __launch_bounds__(256) void k_convX(const float* __restrict__ X,
                                               __hip_bfloat16* __restrict__ Xb) {
    size_t t = (size_t)blockIdx.x * 256 + threadIdx.x;
    const float* p = X + t * 8;
    float4 a = *(const float4*)p;
    float4 b = *(const float4*)(p + 4);
    __hip_bfloat162 o[4] = {
        __float22bfloat162_rn(make_float2(a.x, a.y)),
        __float22bfloat162_rn(make_float2(a.z, a.w)),
        __float22bfloat162_rn(make_float2(b.x, b.y)),
        __float22bfloat162_rn(make_float2(b.z, b.w))};
    *(int4*)(Xb + t * 8) = *(int4*)&o[0];
}

// ---------------------------------------------------------------------------
// Kernel 1: packed int4 -> bf16 W[N][K].
// ---------------------------------------------------------------------------
__global__ __launch_bounds__(256) void k_dequant(const int* __restrict__ pw,
                                                 const float* __restrict__ sc,
                                                 __hip_bfloat16* __restrict__ W) {
    int t = blockIdx.x * 256 + threadIdx.x;
    int row = t >> 8;
    int w0 = (t & 255) << 3;
    const int* p = pw + (size_t)row * 2048 + w0;
    int4 q0 = *(const int4*)p;
    int4 q1 = *(const int4*)(p + 4);
    float s = sc[row * 128 + (w0 >> 4)];
    float ns8 = -8.0f * s;
    int w[8] = {q0.x, q0.y, q0.z, q0.w, q1.x, q1.y, q1.z, q1.w};
    __hip_bfloat162 o[8];
#pragma unroll
    for (int i = 0; i < 8; ++i) {
        float lo = fmaf((float)(w[i] & 15), s, ns8);
        float hi = fmaf((float)(w[i] >> 4), s, ns8);
        o[i] = __float22bfloat162_rn(make_float2(lo, hi));
    }
    __hip_bfloat16* dst = W + (size_t)row * 4096 + w0 * 2;
    *(int4*)dst = *(int4*)&o[0];
    *(int4*)(dst + 8) = *(int4*)&o[4];
}

// ---------------------------------------------------------------------------
// Kernel 2 (tier A): TLP-decoupled GEMM. 128x256 tile, BK=32, RING-3 LDS
// (3 x 24KB = 72KB -> 2 blocks/CU), 512 thr = 8 waves (2Mx4N), per-wave
// 64x64 out (acc=64 VGPR -> fits launch_bounds(512,4) => VGPR<=128 =>
// 2 resident blocks). Overlap comes from the OTHER block's waves (m114
// mechanism), not intra-wave issue order (rounds 6-10 showed schedule-
// invariance at 1 block/CU).
//
// Per step s: stage tile s+2 (3 gloads) -> buf[(s+2)%3]; 8 ds_reads; 16 MFMA;
// boundary vmcnt(3) (drains tile s+1 staged LAST step; leaves s+2's 3) + BAR.
// vmcnt(0) only at the tail.
// Races: stage(s+2) overwrites buf[(s-1)%3], whose reads completed before
// BAR(s-1) (MFMA lgkm-consumed), and stage issues after BAR(s-1). Publish:
// buf[s+1] drained by VMW(3) at end of step s, read after BAR.
//
// LDS layout (r6-verified 0-conflict): 16B slot = chunk*8 + row%8 within
// each 8-row group; linear gload dest, permuted global source.
// ---------------------------------------------------------------------------
__global__ __launch_bounds__(512, 4) void k_gemm11(const __hip_bfloat16* __restrict__ Xb,
                                                   const __hip_bfloat16* __restrict__ Wb,
                                                   float* __restrict__ out) {
    __shared__ __align__(16) short L[3][12288];   // 3 bufs x (A 8KB + B 16KB)

    int bid = blockIdx.x;
    int swz = (bid & 7) * 256 + (bid >> 3);       // XCD-bijective (2048%8==0)
    int bn = swz & 15, bm = swz >> 4;             // bn fastest: 16 blocks share A panel
    int m0 = bm * 128, n0 = bn * 256;
    int t = threadIdx.x, lane = t & 63, wv = t >> 6;
    int wm = wv >> 2, wn = wv & 3;

    // staging source: thread t -> row (t>>5)*8+(t&7) (0..127), chunk (t>>3)&3
    int srow = (t >> 5) * 8 + (t & 7);
    int scol = ((t >> 3) & 3) * 8;
    const __hip_bfloat16* gA = Xb + (size_t)(m0 + srow) * K_TOTAL + scol;
    const __hip_bfloat16* gB = Wb + (size_t)(n0 + srow) * K_TOTAL + scol;
    const __hip_bfloat16* gB2 = gB + (size_t)128 * K_TOTAL;

    auto stage = [&](int b, int T) {
        gload_lds16(gA + T * 32, &L[b][t * 8]);              // A rows 0-127
        gload_lds16(gB + T * 32, &L[b][4096 + t * 8]);       // B rows 0-127
        gload_lds16(gB2 + T * 32, &L[b][8192 + t * 8]);      // B rows 128-255
    };

    // frag-read lane offset (shorts): row r=R+(lane&15), chunk lane>>4
    const int offL = ((lane & 15) >> 3) * 256 + ((lane >> 4) * 8 + (lane & 7)) * 8;

    f32x4 acc[4][4];
#pragma unroll
    for (int i = 0; i < 4; ++i)
#pragma unroll
        for (int j = 0; j < 4; ++j) acc[i][j] = (f32x4)(0.0f);

#define BAR __builtin_amdgcn_s_barrier()
#define PRI(x) __builtin_amdgcn_s_setprio(x)
#define VMW3 { asm volatile("s_waitcnt vmcnt(3)" ::: "memory"); \
               __builtin_amdgcn_sched_barrier(0); }
#define VMW0 { asm volatile("s_waitcnt vmcnt(0)" ::: "memory"); \
               __builtin_amdgcn_sched_barrier(0); }

    // ---- prologue: stage tiles 0,1; drain tile 0 (leave tile 1's 3) ----
    stage(0, 0);
    stage(1, 1);
    VMW3;
    BAR;

    int cur = 0;
    for (int s = 0; s < NT32; ++s) {
        // stage tile s+2 into buf (cur+2)%3
        if (s + 2 < NT32) {
            int b2 = cur + 2; if (b2 >= 3) b2 -= 3;
            stage(b2, s + 2);
        }
        // read this step's fragments
        const short* Lc = &L[cur][0];
        bf16x8 a[4], b[4];
#pragma unroll
        for (int rf = 0; rf < 4; ++rf)
            a[rf] = *(const bf16x8*)&Lc[(wm * 64 + rf * 16) * 32 + offL];
#pragma unroll
        for (int cf = 0; cf < 4; ++cf)
            b[cf] = *(const bf16x8*)&Lc[4096 + (wn * 64 + cf * 16) * 32 + offL];
        // 16 MFMA
        PRI(1);
#pragma unroll
        for (int rf = 0; rf < 4; ++rf)
#pragma unroll
            for (int cf = 0; cf < 4; ++cf)
                acc[rf][cf] = __builtin_amdgcn_mfma_f32_16x16x32_bf16(
                    a[rf], b[cf], acc[rf][cf], 0, 0, 0);
        PRI(0);
        // boundary: publish tile s+1 (staged last step)
        if (s < NT32 - 1) {
            if (s + 2 < NT32) { VMW3 } else { VMW0 }
            BAR;
        }
        ++cur; if (cur >= 3) cur -= 3;
    }
#undef BAR
#undef PRI
#undef VMW3
#undef VMW0

    // ---- epilogue: C/D layout col=lane&15, row=(lane>>4)*4+reg ----
    int col0 = n0 + wn * 64 + (lane & 15);
    int row0 = m0 + wm * 64 + (lane >> 4) * 4;
#pragma unroll
    for (int rf = 0; rf < 4; ++rf)
#pragma unroll
        for (int cf = 0; cf < 4; ++cf) {
            f32x4 v = acc[rf][cf];
            int r = row0 + rf * 16;
            int c = col0 + cf * 16;
#pragma unroll
            for (int q = 0; q < 4; ++q)
                out[(size_t)(r + q) * N_TOTAL + c] = v[q];
        }
}

// ---------------------------------------------------------------------------
// Tier B: m97-structure GEMM, A reg-staged from f32 X (round-5 verified).
// ---------------------------------------------------------------------------
__global__ __launch_bounds__(256) void k_gemm2b(const float* __restrict__ X,
                                                const __hip_bfloat16* __restrict__ Wb,
                                                float* __restrict__ out) {
    __shared__ __align__(16) short As[128 * 32];
    __shared__ __align__(16) short Bs[128 * 32];
    int bid = blockIdx.x;
    int swz = (bid & 7) * 512 + (bid >> 3);
    int bn = swz & 31, bm = swz >> 5;
    int m0 = bm * 128, n0 = bn * 128;
    int t = threadIdx.x, lane = t & 63, wv = t >> 6;
    int wr = wv >> 1, wc = wv & 1;
    f32x4 acc[4][4];
#pragma unroll
    for (int i = 0; i < 4; ++i)
#pragma unroll
        for (int j = 0; j < 4; ++j) acc[i][j] = (f32x4)(0.0f);
    int arow = t >> 2, acol = (t & 3) * 8;
    const float* Agf0 = X + (size_t)(m0 + arow) * K_TOTAL + acol;
    const float* Agf1 = Agf0 + (size_t)64 * K_TOTAL;
    const __hip_bfloat16* Bg0 = Wb + (size_t)(n0 + arow) * K_TOTAL + acol;
    const __hip_bfloat16* Bg1 = Bg0 + (size_t)64 * K_TOTAL;
    float4 xa0 = *(const float4*)(Agf0), xa1 = *(const float4*)(Agf0 + 4);
    float4 xb0 = *(const float4*)(Agf1), xb1 = *(const float4*)(Agf1 + 4);
    for (int kt = 0; kt < NT32; ++kt) {
        if (kt) __syncthreads();
        __hip_bfloat162 oa[4] = {
            __float22bfloat162_rn(make_float2(xa0.x, xa0.y)),
            __float22bfloat162_rn(make_float2(xa0.z, xa0.w)),
            __float22bfloat162_rn(make_float2(xa1.x, xa1.y)),
            __float22bfloat162_rn(make_float2(xa1.z, xa1.w))};
        __hip_bfloat162 ob[4] = {
            __float22bfloat162_rn(make_float2(xb0.x, xb0.y)),
            __float22bfloat162_rn(make_float2(xb0.z, xb0.w)),
            __float22bfloat162_rn(make_float2(xb1.x, xb1.y)),
            __float22bfloat162_rn(make_float2(xb1.z, xb1.w))};
        *(int4*)&As[t * 8] = *(int4*)&oa[0];
        *(int4*)&As[2048 + t * 8] = *(int4*)&ob[0];
        gload_lds16(Bg0 + kt * 32, &Bs[t * 8]);
        gload_lds16(Bg1 + kt * 32, &Bs[2048 + t * 8]);
        __syncthreads();
        if (kt < NT32 - 1) {
            int ko = (kt + 1) * 32;
            xa0 = *(const float4*)(Agf0 + ko);
            xa1 = *(const float4*)(Agf0 + ko + 4);
            xb0 = *(const float4*)(Agf1 + ko);
            xb1 = *(const float4*)(Agf1 + ko + 4);
        }
        bf16x8 a[4], b[4];
        int ro = (lane & 15) * 32 + (lane >> 4) * 8;
#pragma unroll
        for (int i = 0; i < 4; ++i)
            a[i] = *(const bf16x8*)&As[(wr * 64 + i * 16) * 32 + ro];
#pragma unroll
        for (int j = 0; j < 4; ++j)
            b[j] = *(const bf16x8*)&Bs[(wc * 64 + j * 16) * 32 + ro];
#pragma unroll
        for (int i = 0; i < 4; ++i)
#pragma unroll
            for (int j = 0; j < 4; ++j)
                acc[i][j] = __builtin_amdgcn_mfma_f32_16x16x32_bf16(a[i], b[j], acc[i][j], 0, 0, 0);
    }
    int col0 = n0 + wc * 64 + (lane & 15);
    int row0 = m0 + wr * 64 + (lane >> 4) * 4;
#pragma unroll
    for (int i = 0; i < 4; ++i)
#pragma unroll
        for (int j = 0; j < 4; ++j) {
            f32x4 v = acc[i][j];
            int r = row0 + i * 16, c = col0 + j * 16;
#pragma unroll
            for (int q = 0; q < 4; ++q)
                out[(size_t)(r + q) * N_TOTAL + c] = v[q];
        }
}

extern "C" void kernel_launch(void* const* d_in, const int* in_sizes, int n_in,
                              void* d_out, int out_size, void* d_ws, size_t ws_size,
                              hipStream_t stream) {
    const float* X = (const float*)d_in[0];
    const int* PW = (const int*)d_in[1];
    const float* SC = (const float*)d_in[2];
    float* OUT = (float*)d_out;

    const size_t needW = (size_t)N_TOTAL * K_TOTAL * 2;            // 33.5 MB
    const size_t needX = needW + (size_t)M_TOTAL * K_TOTAL * 2;    // +134 MB

    if (ws_size >= needX) {
        __hip_bfloat16* Wb = (__hip_bfloat16*)d_ws;
        __hip_bfloat16* Xb = (__hip_bfloat16*)((char*)d_ws + needW);
        k_convX<<<dim3(32768), dim3(256), 0, stream>>>(X, Xb);
        k_dequant<<<dim3(4096), dim3(256), 0, stream>>>(PW, SC, Wb);
        k_gemm11<<<dim3((M_TOTAL / 128) * (N_TOTAL / 256)), dim3(512), 0, stream>>>(Xb, Wb, OUT);
    } else if (ws_size >= needW) {
        __hip_bfloat16* Wb = (__hip_bfloat16*)d_ws;
        k_dequant<<<dim3(4096), dim3(256), 0, stream>>>(PW, SC, Wb);
        k_gemm2b<<<dim3((M_TOTAL / 128) * (N_TOTAL / 128)), dim3(256), 0, stream>>>(X, Wb, OUT);
    }
}

// Round 13
// 643.710 us; speedup vs baseline: 1.2965x; 1.2965x over previous
//
#include <hip/hip_runtime.h>
#include <hip/hip_bf16.h>
#include <stdint.h>

#define M_TOTAL 16384
#define N_TOTAL 4096
#define K_TOTAL 4096
#define NSTEP (K_TOTAL / 64)   // 64 K-steps of 64
#define NT32 (K_TOTAL / 32)

typedef __attribute__((ext_vector_type(8))) short bf16x8;
typedef __attribute__((ext_vector_type(4))) float f32x4;
typedef __attribute__((ext_vector_type(16))) float f32x16;

__device__ __forceinline__ void gload_lds16(const void* g, void* l) {
    __builtin_amdgcn_global_load_lds(
        (const __attribute__((address_space(1))) uint32_t*)g,
        (__attribute__((address_space(3))) uint32_t*)l, 16, 0, 0);
}

// ---------------------------------------------------------------------------
// Kernel 0: X f32 -> bf16.
// ---------------------------------------------------------------------------
__global__ __launch_bounds__(256) void k_convX(const float* __restrict__ X,
                                               __hip_bfloat16* __restrict__ Xb) {
    size_t t = (size_t)blockIdx.x * 256 + threadIdx.x;
    const float* p = X + t * 8;
    float4 a = *(const float4*)p;
    float4 b = *(const float4*)(p + 4);
    __hip_bfloat162 o[4] = {
        __float22bfloat162_rn(make_float2(a.x, a.y)),
        __float22bfloat162_rn(make_float2(a.z, a.w)),
        __float22bfloat162_rn(make_float2(b.x, b.y)),
        __float22bfloat162_rn(make_float2(b.z, b.w))};
    *(int4*)(Xb + t * 8) = *(int4*)&o[0];
}

// ---------------------------------------------------------------------------
// Kernel 1: packed int4 -> bf16 W[N][K].
// ---------------------------------------------------------------------------
__global__ __launch_bounds__(256) void k_dequant(const int* __restrict__ pw,
                                                 const float* __restrict__ sc,
                                                 __hip_bfloat16* __restrict__ W) {
    int t = blockIdx.x * 256 + threadIdx.x;
    int row = t >> 8;
    int w0 = (t & 255) << 3;
    const int* p = pw + (size_t)row * 2048 + w0;
    int4 q0 = *(const int4*)p;
    int4 q1 = *(const int4*)(p + 4);
    float s = sc[row * 128 + (w0 >> 4)];
    float ns8 = -8.0f * s;
    int w[8] = {q0.x, q0.y, q0.z, q0.w, q1.x, q1.y, q1.z, q1.w};
    __hip_bfloat162 o[8];
#pragma unroll
    for (int i = 0; i < 8; ++i) {
        float lo = fmaf((float)(w[i] & 15), s, ns8);
        float hi = fmaf((float)(w[i] >> 4), s, ns8);
        o[i] = __float22bfloat162_rn(make_float2(lo, hi));
    }
    __hip_bfloat16* dst = W + (size_t)row * 4096 + w0 * 2;
    *(int4*)dst = *(int4*)&o[0];
    *(int4*)(dst + 8) = *(int4*)&o[4];
}

// ---------------------------------------------------------------------------
// Kernel 2 (tier A): r12 structure (8-phase, 256x256, BK=64, 32x32x16 MFMA)
// with RACE-FIXED stage rotation.
//
// Reads (unchanged): P1: A[ar0-1][kc0-1], B[kc0-1]; P2: A[ar2-3][kc0-1],
// A[ar0-1][kc2-3]; P3: A[ar2-3][kc2-3], B[kc2-3]; P4: none. (P5-P8 mirror.)
//
// Stage rotation (each slot >= 1 end-barrier after region's last read is
// CONSUMED; consumption forces lgkm-drain, barrier makes it block-wide):
//   P1: A(s+1)h0 -> b1A  [b1A last read P7'; consumed P8' MFMA; P1 > P8'-bar]
//   P2: A(s+1)h1 -> b1A  [same]
//   P3: B(s+1)h1 -> b1B  [b1B-h1 last read P7' (RDB2,wnh=1); consumed P7']
//   P4: B(s+2)h0 -> b0B  [b0B-h0 last read P3 (RDB2,wnh=0); consumed P3 MFMA]
//   P5: B(s+2)h1 -> b0B  [b0B-h1 last read P3; consumed P3]
//   P6: A(s+2)h0 -> b0A  [b0A last read P3 (A1 kc23); consumed P4 MFMA]
//   P7: A(s+2)h1 -> b0A  [same]
//   P8: B(s+3)h0 -> b1B  [b1B-h0 last read P7 (RDB2); consumed P7 MFMA]
//   (B(s+3)h1 deferred to next iter's P3.)
// Ledger: VMW(2) at P4-end publishes [B(s+1)h0(prev P8), A(s+1)h0/h1,
// B(s+1)h1] (8 loads) leaving B(s+2)h0's 2; VMW(2) at P8-end publishes all
// of tile s+2 (8 loads) leaving B(s+3)h0's 2. Invariant: 2 outstanding at
// iter entry. g = (s+2<NSTEP); g==g3 since s even. Tail: VMW(0).
//
// Frag layout (32x32x16): A/B row=lane&31, k=(lane>>5)*8+e; C/D col=lane&31,
// row=(reg&3)+8*(reg>>2)+4*(lane>>5) [m74/m101]. LDS slot scheme unchanged
// (0-conflict; 32x32 read pattern re-derived bank-uniform).
// ---------------------------------------------------------------------------
__global__ __launch_bounds__(512, 2) void k_gemm13(const __hip_bfloat16* __restrict__ Xb,
                                                   const __hip_bfloat16* __restrict__ Wb,
                                                   float* __restrict__ out) {
    __shared__ __align__(16) short L[2][2][2][8192];  // [buf][A/B][half][16KB]

    int bid = blockIdx.x;
    int swz = (bid & 7) * 128 + (bid >> 3);           // XCD-bijective (1024%8==0)
    int bn = swz & 15, bm = swz >> 4;
    int m0 = bm * 256, n0 = bn * 256;
    int t = threadIdx.x, lane = t & 63, wv = t >> 6;
    int wm = wv >> 2, wn = wv & 3, wnh = wn >> 1;

    int srow = (t >> 6) * 8 + (t & 7);
    int scol = ((t >> 3) & 7) * 8;
    const __hip_bfloat16* gA = Xb + (size_t)(m0 + srow) * K_TOTAL + scol;
    const __hip_bfloat16* gB = Wb + (size_t)(n0 + srow) * K_TOTAL + scol;

    auto stA = [&](int b, int h, int s_) {
        gload_lds16(gA + (size_t)(h * 128) * K_TOTAL + s_ * 64, &L[b][0][h][t * 8]);
        gload_lds16(gA + (size_t)(h * 128 + 64) * K_TOTAL + s_ * 64, &L[b][0][h][4096 + t * 8]);
    };
    auto stB = [&](int b, int h, int s_) {
        gload_lds16(gB + (size_t)(h * 128) * K_TOTAL + s_ * 64, &L[b][1][h][t * 8]);
        gload_lds16(gB + (size_t)(h * 128 + 64) * K_TOTAL + s_ * 64, &L[b][1][h][4096 + t * 8]);
    };

    const int l31 = lane & 31, lhi = lane >> 5;
    const int lof = (l31 >> 3) * 512 + lhi * 64 + (lane & 7) * 8;  // + kc*128
    const int cb0 = (wn & 1) * 4096;

    f32x16 acc[4][2];
#pragma unroll
    for (int f = 0; f < 4; ++f)
#pragma unroll
        for (int j = 0; j < 2; ++j) acc[f][j] = (f32x16)(0.0f);

    bf16x8 A0[8], A1[8], Bv[8];

#define BAR __builtin_amdgcn_s_barrier()
#define PRI(x) __builtin_amdgcn_s_setprio(x)
#define VMW(n) { asm volatile("s_waitcnt vmcnt(" #n ")" ::: "memory"); \
                 __builtin_amdgcn_sched_barrier(0); }

#define RDA(dst, arb, kb) { _Pragma("unroll") for (int u = 0; u < 2; ++u) \
    _Pragma("unroll") for (int k = 0; k < 2; ++k) { \
        const int ar = (arb) + u; \
        dst[u * 4 + (kb) + k] = *(const bf16x8*)&LA[(ar >> 1) * 4096 + \
            (ar & 1) * 2048 + lof + ((kb) + k) * 128]; } }
#define RDB(kb) { _Pragma("unroll") for (int u = 0; u < 2; ++u) \
    _Pragma("unroll") for (int k = 0; k < 2; ++k) \
        Bv[u * 4 + (kb) + k] = *(const bf16x8*)&LB[cb0 + u * 2048 + lof + ((kb) + k) * 128]; }
#define MM8(AV, arb, kb) { _Pragma("unroll") for (int k = 0; k < 2; ++k) \
    _Pragma("unroll") for (int u = 0; u < 2; ++u) \
    _Pragma("unroll") for (int c = 0; c < 2; ++c) \
        acc[(arb) + u][c] = __builtin_amdgcn_mfma_f32_32x32x16_bf16( \
            AV[u * 4 + (kb) + k], Bv[c * 4 + (kb) + k], acc[(arb) + u][c], 0, 0, 0); }

    // ---- prologue: B(0) both halves, A(0) both halves, B(1)h0 ----
    stB(0, 0, 0); stB(0, 1, 0);
    stA(0, 0, 0); stA(0, 1, 0);
    stB(1, 0, 1);
    VMW(2);          // publish B(0),A(0); leave B(1)h0's 2
    BAR;

    for (int i = 0; i < NSTEP / 2; ++i) {
        const int s = 2 * i;
        const bool g = (s + 2 < NSTEP);
        // ======== K-step s (buf 0) ========
        {
            const short* LA = &L[0][0][wm][0];
            const short* LB = &L[0][1][wnh][0];
            // P1
            RDA(A0, 0, 0) RDB(0)
            stA(1, 0, s + 1);
            BAR; PRI(1); MM8(A0, 0, 0) PRI(0); BAR;
            // P2
            RDA(A1, 2, 0) RDA(A0, 0, 2)
            stA(1, 1, s + 1);
            BAR; PRI(1); MM8(A1, 2, 0) PRI(0); BAR;
            // P3
            RDA(A1, 2, 2) RDB(2)
            stB(1, 1, s + 1);
            BAR; PRI(1); MM8(A0, 0, 2) PRI(0); BAR;
            // P4
            if (g) stB(0, 0, s + 2);
            BAR; PRI(1); MM8(A1, 2, 2) PRI(0);
            if (g) { VMW(2) } else { VMW(0) }
            BAR;
        }
        // ======== K-step s+1 (buf 1) ========
        {
            const short* LA = &L[1][0][wm][0];
            const short* LB = &L[1][1][wnh][0];
            // P5
            RDA(A0, 0, 0) RDB(0)
            if (g) stB(0, 1, s + 2);
            BAR; PRI(1); MM8(A0, 0, 0) PRI(0); BAR;
            // P6
            RDA(A1, 2, 0) RDA(A0, 0, 2)
            if (g) stA(0, 0, s + 2);
            BAR; PRI(1); MM8(A1, 2, 0) PRI(0); BAR;
            // P7
            RDA(A1, 2, 2) RDB(2)
            if (g) stA(0, 1, s + 2);
            BAR; PRI(1); MM8(A0, 0, 2) PRI(0); BAR;
            // P8
            if (g) stB(1, 0, s + 3);
            BAR; PRI(1); MM8(A1, 2, 2) PRI(0);
            if (g) { VMW(2) } else { VMW(0) }
            BAR;
        }
    }
#undef RDA
#undef RDB
#undef MM8
#undef BAR
#undef PRI
#undef VMW

    // ---- epilogue: C/D col=lane&31, row=(reg&3)+8*(reg>>2)+4*(lane>>5) ----
#pragma unroll
    for (int f = 0; f < 4; ++f)
#pragma unroll
        for (int j = 0; j < 2; ++j) {
            f32x16 v = acc[f][j];
            int c = n0 + wn * 64 + j * 32 + l31;
            int rbase = m0 + wm * 128 + f * 32 + 4 * lhi;
#pragma unroll
            for (int gq = 0; gq < 4; ++gq)
#pragma unroll
                for (int q = 0; q < 4; ++q)
                    out[(size_t)(rbase + 8 * gq + q) * N_TOTAL + c] = v[gq * 4 + q];
        }
}

// ---------------------------------------------------------------------------
// Tier B: m97-structure GEMM, A reg-staged from f32 X (round-5 verified).
// ---------------------------------------------------------------------------
__global__ __launch_bounds__(256) void k_gemm2b(const float* __restrict__ X,
                                                const __hip_bfloat16* __restrict__ Wb,
                                                float* __restrict__ out) {
    __shared__ __align__(16) short As[128 * 32];
    __shared__ __align__(16) short Bs[128 * 32];
    int bid = blockIdx.x;
    int swz = (bid & 7) * 512 + (bid >> 3);
    int bn = swz & 31, bm = swz >> 5;
    int m0 = bm * 128, n0 = bn * 128;
    int t = threadIdx.x, lane = t & 63, wv = t >> 6;
    int wr = wv >> 1, wc = wv & 1;
    f32x4 acc[4][4];
#pragma unroll
    for (int i = 0; i < 4; ++i)
#pragma unroll
        for (int j = 0; j < 4; ++j) acc[i][j] = (f32x4)(0.0f);
    int arow = t >> 2, acol = (t & 3) * 8;
    const float* Agf0 = X + (size_t)(m0 + arow) * K_TOTAL + acol;
    const float* Agf1 = Agf0 + (size_t)64 * K_TOTAL;
    const __hip_bfloat16* Bg0 = Wb + (size_t)(n0 + arow) * K_TOTAL + acol;
    const __hip_bfloat16* Bg1 = Bg0 + (size_t)64 * K_TOTAL;
    float4 xa0 = *(const float4*)(Agf0), xa1 = *(const float4*)(Agf0 + 4);
    float4 xb0 = *(const float4*)(Agf1), xb1 = *(const float4*)(Agf1 + 4);
    for (int kt = 0; kt < NT32; ++kt) {
        if (kt) __syncthreads();
        __hip_bfloat162 oa[4] = {
            __float22bfloat162_rn(make_float2(xa0.x, xa0.y)),
            __float22bfloat162_rn(make_float2(xa0.z, xa0.w)),
            __float22bfloat162_rn(make_float2(xa1.x, xa1.y)),
            __float22bfloat162_rn(make_float2(xa1.z, xa1.w))};
        __hip_bfloat162 ob[4] = {
            __float22bfloat162_rn(make_float2(xb0.x, xb0.y)),
            __float22bfloat162_rn(make_float2(xb0.z, xb0.w)),
            __float22bfloat162_rn(make_float2(xb1.x, xb1.y)),
            __float22bfloat162_rn(make_float2(xb1.z, xb1.w))};
        *(int4*)&As[t * 8] = *(int4*)&oa[0];
        *(int4*)&As[2048 + t * 8] = *(int4*)&ob[0];
        gload_lds16(Bg0 + kt * 32, &Bs[t * 8]);
        gload_lds16(Bg1 + kt * 32, &Bs[2048 + t * 8]);
        __syncthreads();
        if (kt < NT32 - 1) {
            int ko = (kt + 1) * 32;
            xa0 = *(const float4*)(Agf0 + ko);
            xa1 = *(const float4*)(Agf0 + ko + 4);
            xb0 = *(const float4*)(Agf1 + ko);
            xb1 = *(const float4*)(Agf1 + ko + 4);
        }
        bf16x8 a[4], b[4];
        int ro = (lane & 15) * 32 + (lane >> 4) * 8;
#pragma unroll
        for (int i = 0; i < 4; ++i)
            a[i] = *(const bf16x8*)&As[(wr * 64 + i * 16) * 32 + ro];
#pragma unroll
        for (int j = 0; j < 4; ++j)
            b[j] = *(const bf16x8*)&Bs[(wc * 64 + j * 16) * 32 + ro];
#pragma unroll
        for (int i = 0; i < 4; ++i)
#pragma unroll
            for (int j = 0; j < 4; ++j)
                acc[i][j] = __builtin_amdgcn_mfma_f32_16x16x32_bf16(a[i], b[j], acc[i][j], 0, 0, 0);
    }
    int col0 = n0 + wc * 64 + (lane & 15);
    int row0 = m0 + wr * 64 + (lane >> 4) * 4;
#pragma unroll
    for (int i = 0; i < 4; ++i)
#pragma unroll
        for (int j = 0; j < 4; ++j) {
            f32x4 v = acc[i][j];
            int r = row0 + i * 16, c = col0 + j * 16;
#pragma unroll
            for (int q = 0; q < 4; ++q)
                out[(size_t)(r + q) * N_TOTAL + c] = v[q];
        }
}

extern "C" void kernel_launch(void* const* d_in, const int* in_sizes, int n_in,
                              void* d_out, int out_size, void* d_ws, size_t ws_size,
                              hipStream_t stream) {
    const float* X = (const float*)d_in[0];
    const int* PW = (const int*)d_in[1];
    const float* SC = (const float*)d_in[2];
    float* OUT = (float*)d_out;

    const size_t needW = (size_t)N_TOTAL * K_TOTAL * 2;            // 33.5 MB
    const size_t needX = needW + (size_t)M_TOTAL * K_TOTAL * 2;    // +134 MB

    if (ws_size >= needX) {
        __hip_bfloat16* Wb = (__hip_bfloat16*)d_ws;
        __hip_bfloat16* Xb = (__hip_bfloat16*)((char*)d_ws + needW);
        k_convX<<<dim3(32768), dim3(256), 0, stream>>>(X, Xb);
        k_dequant<<<dim3(4096), dim3(256), 0, stream>>>(PW, SC, Wb);
        k_gemm13<<<dim3((M_TOTAL / 256) * (N_TOTAL / 256)), dim3(512), 0, stream>>>(Xb, Wb, OUT);
    } else if (ws_size >= needW) {
        __hip_bfloat16* Wb = (__hip_bfloat16*)d_ws;
        k_dequant<<<dim3(4096), dim3(256), 0, stream>>>(PW, SC, Wb);
        k_gemm2b<<<dim3((M_TOTAL / 128) * (N_TOTAL / 128)), dim3(256), 0, stream>>>(X, Wb, OUT);
    }
}